// Round 11
// baseline (1389.133 us; speedup 1.0000x reference)
//
#include <hip/hip_runtime.h>

#define NN 50000
#define NE 1600000
#define DIM 32
#define HS 0.1f
#define NBPS 782       // cdiv(NN, 64) blocks per sign
#define NNB 196        // cdiv(NN, 256)
#define SBIN 256       // nodes per bin (orig-id and sorted-pos space coincide per bin)
#define NBIN 196       // cdiv(NN, SBIN)
#define AB 391         // cdiv(NE, 4096) phase-A blocks per sign
#define WCAP 22528     // scatB LDS window capacity (ushorts, 45KB)

static inline int cdiv(int a, int b) { return (a + b - 1) / b; }

typedef unsigned short ushort_t;

// NO non-temporal hints anywhere (r1/r2 -480us, r8 -250us: line-sharing).
// NO deep global-atomic chains (r3 377us, r6 93us, r10: hist's 144us was
// 6.4M device-scope atomics -> 50MB fabric write traffic; now eliminated
// by bin-local LDS degree counting).

// bf16x4 (uint2) -> float4
__device__ __forceinline__ float4 bf4_to_f4(uint2 u) {
    float4 v;
    v.x = __uint_as_float(u.x << 16);
    v.y = __uint_as_float(u.x & 0xffff0000u);
    v.z = __uint_as_float(u.y << 16);
    v.w = __uint_as_float(u.y & 0xffff0000u);
    return v;
}
__device__ __forceinline__ unsigned pack_bf2(float a, float b) {
    unsigned ua = __float_as_uint(a);
    ua = (ua + 0x7fffu + ((ua >> 16) & 1u)) >> 16;
    unsigned ub = __float_as_uint(b);
    ub = (ub + 0x7fffu + ((ub >> 16) & 1u)) & 0xffff0000u;
    return ua | ub;
}
__device__ __forceinline__ uint4 pack_bf8(float4 a, float4 b) {
    return make_uint4(pack_bf2(a.x, a.y), pack_bf2(a.z, a.w),
                      pack_bf2(b.x, b.y), pack_bf2(b.z, b.w));
}

// ---------------- radix CSR build (orig-space bins; no global atomics) ----------------

// count matrix gcnt[blk][bin]: edges per (phase-A block, dst-bin), bin = dst>>8
__global__ __launch_bounds__(512) void k_countA(const int* __restrict__ d0,
                        const int* __restrict__ d1,
                        int* __restrict__ gc0, int* __restrict__ gc1) {
    __shared__ int lc[NBIN];
    int b = blockIdx.x, sg = b & 1, blk = b >> 1;
    int t = threadIdx.x;
    if (t < NBIN) lc[t] = 0;
    __syncthreads();
    const int* dst = sg ? d1 : d0;
#pragma unroll
    for (int i = 0; i < 8; i++) {
        int e = blk * 4096 + i * 512 + t;
        if (e < NE) atomicAdd(&lc[dst[e] >> 8], 1);
    }
    __syncthreads();
    int* gc = sg ? gc1 : gc0;
    if (t < NBIN) gc[blk * NBIN + t] = lc[t];
}

// per-bin exclusive scan over blocks + bin totals
__global__ __launch_bounds__(512) void k_scanM1(int* __restrict__ gc0,
                                                int* __restrict__ gc1,
                                                int* __restrict__ bint) {
    __shared__ int s[512];
    int b = blockIdx.x, sg = b & 1, bin = b >> 1;
    int* gc = sg ? gc1 : gc0;
    int t = threadIdx.x;
    int v = (t < AB) ? gc[t * NBIN + bin] : 0;
    s[t] = v;
    __syncthreads();
    for (int off = 1; off < 512; off <<= 1) {
        int a = (t >= off) ? s[t - off] : 0;
        __syncthreads();
        s[t] += a;
        __syncthreads();
    }
    if (t < AB) gc[t * NBIN + bin] = s[t] - v;
    if (t == AB - 1) bint[sg * NBIN + bin] = s[t];
}

// exclusive scan of bin totals -> staging bases
__global__ __launch_bounds__(256) void k_scanM2(const int* __restrict__ bint,
                                                int* __restrict__ binbase) {
    __shared__ int s[256];
    int t = threadIdx.x;
    for (int sg = 0; sg < 2; sg++) {
        int v = (t < NBIN) ? bint[sg * NBIN + t] : 0;
        s[t] = v;
        __syncthreads();
        for (int off = 1; off < 256; off <<= 1) {
            int a = (t >= off) ? s[t - off] : 0;
            __syncthreads();
            s[t] += a;
            __syncthreads();
        }
        if (t < NBIN) binbase[sg * NBIN + t] = s[t] - v;
        __syncthreads();
    }
}

// bin-group records (src<<8 | dst&255) into staging at precomputed offsets
__global__ __launch_bounds__(512) void k_scatA(const int* __restrict__ s0s,
                        const int* __restrict__ s0d,
                        const int* __restrict__ s1s, const int* __restrict__ s1d,
                        const int* __restrict__ gc0, const int* __restrict__ gc1,
                        const int* __restrict__ binbase,
                        unsigned* __restrict__ gst0, unsigned* __restrict__ gst1) {
    __shared__ int lc[NBIN];
    __shared__ int lst[NBIN];
    __shared__ int gch[NBIN];
    __shared__ unsigned stag[4096];
    __shared__ ushort_t bos[4096];
    int b = blockIdx.x, sg = b & 1, blk = b >> 1;
    int t = threadIdx.x;
    if (t < NBIN) lc[t] = 0;
    __syncthreads();
    const int* src = sg ? s1s : s0s;
    const int* dst = sg ? s1d : s0d;
    const int* gc  = sg ? gc1 : gc0;
    unsigned er[8]; int ebin[8]; int erk[8];
#pragma unroll
    for (int i = 0; i < 8; i++) {
        int e = blk * 4096 + i * 512 + t;
        ebin[i] = -1;
        if (e < NE) {
            int d = dst[e];
            int bin = d >> 8;
            ebin[i] = bin;
            er[i] = ((unsigned)src[e] << 8) | (unsigned)(d & 255);
            erk[i] = atomicAdd(&lc[bin], 1);
        }
    }
    __syncthreads();
    if (t < NBIN) lst[t] = lc[t];
    __syncthreads();
    for (int off = 1; off < NBIN; off <<= 1) {
        int a = (t >= off && t < NBIN) ? lst[t - off] : 0;
        __syncthreads();
        if (t < NBIN) lst[t] += a;
        __syncthreads();
    }
    if (t < NBIN) {
        lst[t] -= lc[t];
        gch[t] = binbase[sg * NBIN + t] + gc[blk * NBIN + t];
    }
    __syncthreads();
#pragma unroll
    for (int i = 0; i < 8; i++) {
        if (ebin[i] >= 0) {
            int slot = lst[ebin[i]] + erk[i];
            stag[slot] = er[i];
            bos[slot] = (ushort_t)ebin[i];
        }
    }
    __syncthreads();
    unsigned* gst = sg ? gst1 : gst0;
    int tot = (blk * 4096 + 4096 <= NE) ? 4096 : (NE - blk * 4096);
#pragma unroll
    for (int i = 0; i < 8; i++) {
        int slot = i * 512 + t;
        if (slot < tot) {
            int bin = bos[slot];
            gst[gch[bin] + (slot - lst[bin])] = stag[slot];
        }
    }
}

// per-bin: degrees via LDS counting (replaces global hist), bin-local
// descending counting-sort -> cnt/pos/perm/dis, within-bin padded row prefix
__global__ __launch_bounds__(256) void k_degB(
        const unsigned* __restrict__ gst0, const unsigned* __restrict__ gst1,
        const int* __restrict__ bint, const int* __restrict__ binbase,
        int* __restrict__ c0, int* __restrict__ c1,
        int* __restrict__ pos0, int* __restrict__ pos1,
        int* __restrict__ perm0, int* __restrict__ perm1,
        float* __restrict__ q0, float* __restrict__ q1,
        int* __restrict__ r0, int* __restrict__ r1,
        int* __restrict__ bt0, int* __restrict__ bt1) {
    __shared__ int deg[SBIN];
    __shared__ int dh[256];
    __shared__ int spd[SBIN];
    __shared__ int s[256];
    int b = blockIdx.x, sg = b & 1, bin = b >> 1;
    int t = threadIdx.x;
    const unsigned* gst = sg ? gst1 : gst0;
    int p0 = bin * SBIN;
    int nn = NN - p0; if (nn > SBIN) nn = SBIN;
    deg[t] = 0; dh[t] = 0;
    __syncthreads();
    int cntr = bint[sg * NBIN + bin];
    int base = binbase[sg * NBIN + bin];
    for (int i = t; i < cntr; i += 256)
        atomicAdd(&deg[gst[base + i] & 255u], 1);
    __syncthreads();
    int d = 0, dc = 0;
    if (t < nn) {
        d = deg[t];
        dc = d > 255 ? 255 : d;
        atomicAdd(&dh[dc], 1);
    }
    __syncthreads();
    // descending exclusive scan of degree-value histogram
    s[t] = dh[255 - t];
    __syncthreads();
    for (int off = 1; off < 256; off <<= 1) {
        int a = (t >= off) ? s[t - off] : 0;
        __syncthreads();
        s[t] += a;
        __syncthreads();
    }
    int ex = (t == 0) ? 0 : s[t - 1];
    __syncthreads();
    dh[255 - t] = ex;          // dh[d] = first rank for degree d (descending)
    __syncthreads();
    if (t < nn) {
        int r = atomicAdd(&dh[dc], 1);   // unique rank within bin
        int* cnt = sg ? c1 : c0;
        int* pos = sg ? pos1 : pos0;
        int* perm = sg ? perm1 : perm0;
        float* dq = sg ? q1 : q0;
        cnt[p0 + t] = d;
        pos[p0 + t] = p0 + r;
        perm[p0 + r] = p0 + t;
        dq[p0 + r] = rsqrtf((float)d + 1.0f);
        spd[r] = (d + 7) & ~7;
    }
    __syncthreads();
    // inclusive scan of padded degrees over ranks -> relative row prefix
    int v = (t < nn) ? spd[t] : 0;
    s[t] = v;
    __syncthreads();
    for (int off = 1; off < 256; off <<= 1) {
        int a = (t >= off) ? s[t - off] : 0;
        __syncthreads();
        s[t] += a;
        __syncthreads();
    }
    int* rp = sg ? r1 : r0;
    int* bt = sg ? bt1 : bt0;
    if (t < nn) rp[p0 + t + 1] = s[t];
    if (t == nn - 1) bt[bin] = s[t];
}

// exclusive scan of bin CSR totals (in place: bt becomes bin start)
__global__ __launch_bounds__(256) void k_binscan(int* __restrict__ bt0,
                                                 int* __restrict__ bt1) {
    __shared__ int s[256];
    int sg = blockIdx.x, t = threadIdx.x;
    int* bt = sg ? bt1 : bt0;
    int v = (t < NBIN) ? bt[t] : 0;
    s[t] = v;
    __syncthreads();
    for (int off = 1; off < 256; off <<= 1) {
        int a = (t >= off) ? s[t - off] : 0;
        __syncthreads();
        s[t] += a;
        __syncthreads();
    }
    if (t < NBIN) bt[t] = s[t] - v;
}

// row_ptr absolute: add bin starts
__global__ void k_rowfix(int* __restrict__ r0, int* __restrict__ r1,
                         const int* __restrict__ bt0, const int* __restrict__ bt1) {
    int b = blockIdx.x, sg = b & 1;
    int g = (b >> 1) * 256 + (int)threadIdx.x;
    int* rp = sg ? r1 : r0;
    const int* bt = sg ? bt1 : bt0;
    if (g < NN) rp[g + 1] += bt[g >> 8];
    if (g == 0) rp[0] = 0;
}

// per-bin LDS-window scatter + pad, fully-coalesced uint4 write-out.
// Records' dst-local mapped to bin-local rank via LDS; src mapped to global
// sorted position via pos[] gather (200KB, L2-resident).
__global__ __launch_bounds__(512) void k_scatB(const int* __restrict__ r0,
                        const int* __restrict__ r1,
                        const unsigned* __restrict__ gst0,
                        const unsigned* __restrict__ gst1,
                        const int* __restrict__ bint, const int* __restrict__ binbase,
                        const int* __restrict__ pos0, const int* __restrict__ pos1,
                        ushort_t* __restrict__ w0, ushort_t* __restrict__ w1) {
    __shared__ uint4 winq[WCAP / 8];
    __shared__ int lrp[SBIN + 1];
    __shared__ int lfill[SBIN];
    __shared__ int lpos[SBIN];
    ushort_t* win = (ushort_t*)winq;
    int b = blockIdx.x, sg = b & 1, bin = b >> 1;
    int t = threadIdx.x;
    const int* rp = sg ? r1 : r0;
    const unsigned* gst = sg ? gst1 : gst0;
    const int* pos = sg ? pos1 : pos0;
    ushort_t* cw = sg ? w1 : w0;
    int p0 = bin * SBIN;
    int nn = NN - p0; if (nn > SBIN) nn = SBIN;
    if (t <= nn) lrp[t] = rp[p0 + t];
    if (t < nn) { lfill[t] = 0; lpos[t] = pos[p0 + t] - p0; }
    __syncthreads();
    int wb = lrp[0];
    int wl = lrp[nn] - wb;
    int cnt = bint[sg * NBIN + bin];
    int base = binbase[sg * NBIN + bin];
    if (wl <= WCAP) {
        for (int i = t; i < cnt; i += 512) {
            unsigned e = gst[base + i];
            int rl = lpos[e & 255u];
            int ps = pos[e >> 8];
            int ofs = atomicAdd(&lfill[rl], 1);
            win[lrp[rl] - wb + ofs] = (ushort_t)ps;
        }
        __syncthreads();
        for (int ln = t; ln < nn; ln += 512) {
            int e0 = lrp[ln] - wb + lfill[ln], e1 = lrp[ln + 1] - wb;
            for (int j = e0; j < e1; j++) win[j] = (ushort_t)NN;
        }
        __syncthreads();
        uint4* dst4 = (uint4*)(cw + wb);   // wb multiple of 8 -> 16B aligned
        int nq = wl >> 3;
        for (int i = t; i < nq; i += 512) dst4[i] = winq[i];
    } else {
        for (int i = t; i < cnt; i += 512) {
            unsigned e = gst[base + i];
            int rl = lpos[e & 255u];
            int ps = pos[e >> 8];
            int ofs = atomicAdd(&lfill[rl], 1);
            cw[lrp[rl] + ofs] = (ushort_t)ps;
        }
        __syncthreads();
        for (int ln = t; ln < nn; ln += 512) {
            int e0 = lrp[ln] + lfill[ln], e1 = lrp[ln + 1];
            for (int j = e0; j < e1; j++) cw[j] = (ushort_t)NN;
        }
    }
}

// zero row NN of all six table buffers (16 uints each)
struct ZArgs { unsigned* p[6]; };
__global__ void k_zrow(ZArgs z) {
    int t = threadIdx.x;
    if (t < 96) z.p[t >> 4][(size_t)NN * 16 + (t & 15)] = 0u;
}

// T_base[pos[n]] = bf16(dis[n]*(x@W)[n]), x_cur = x
__global__ __launch_bounds__(256) void k_matmul(const float* __restrict__ src,
                                                const float* __restrict__ W,
                                                const int* __restrict__ cnt,
                                                const int* __restrict__ pos,
                                                uint2* __restrict__ xw,
                                                float* __restrict__ copy_out) {
    __shared__ float sW[DIM * DIM];
    __shared__ float sX[32 * 33];
    int t = threadIdx.x;
#pragma unroll
    for (int k = 0; k < 4; k++) { int i = k * 256 + t; sW[i] = W[i]; }
    size_t base = (size_t)blockIdx.x * 32 * DIM;
#pragma unroll
    for (int k = 0; k < 4; k++) {
        int i = k * 256 + t;
        size_t g = base + i;
        float v = 0.f;
        if (g < (size_t)NN * DIM) {
            v = src[g];
            copy_out[g] = v;
        }
        sX[(i >> 5) * 33 + (i & 31)] = v;
    }
    __syncthreads();
    int r = t >> 3, oct = t & 7;
    int row = blockIdx.x * 32 + r;
    if (row >= NN) return;
    float a0 = 0.f, a1 = 0.f, a2 = 0.f, a3 = 0.f;
    const float* xr = &sX[r * 33];
#pragma unroll
    for (int i = 0; i < DIM; i++) {
        float xv = xr[i];
        const float* wr = &sW[i * DIM + oct * 4];
        a0 = fmaf(xv, wr[0], a0);
        a1 = fmaf(xv, wr[1], a1);
        a2 = fmaf(xv, wr[2], a2);
        a3 = fmaf(xv, wr[3], a3);
    }
    float dn = rsqrtf((float)cnt[row] + 1.0f);
    a0 *= dn; a1 *= dn; a2 *= dn; a3 *= dn;
    xw[(size_t)pos[row] * 8 + oct] = make_uint2(pack_bf2(a0, a1), pack_bf2(a2, a3));
}

// ---------------- fused stage kernel (bin-local degree-sorted space) ----------------

struct SignP {
    const int* row_ptr; const ushort_t* cw; const float* dis;
    const int* perm;
    const uint4* xw_in; uint4* xw_out; const uint4* xw_base;
    uint4* acc;                      // bf16, row stride 4 uint4
    float* x_cur;
    const float* W; const float* b; const float* wt;
    float* zout;
};
struct StageArgs { SignP s[2]; float t, stage_coef; int mode; };

#define EDGE_ADD(u)                                                     \
    {                                                                   \
        float4 vA = bf4_to_f4(make_uint2((u).x, (u).y));                \
        float4 vB = bf4_to_f4(make_uint2((u).z, (u).w));                \
        sum0.x += vA.x; sum0.y += vA.y; sum0.z += vA.z; sum0.w += vA.w; \
        sum1.x += vB.x; sum1.y += vB.y; sum1.z += vB.z; sum1.w += vB.w; \
    }

__global__ __launch_bounds__(256) void k_stage(StageArgs A) {
    int sg = blockIdx.x & 1;
    int blk = blockIdx.x >> 1;
    SignP P = A.s[sg];

    __shared__ float sW[DIM * DIM];   // 4 KB
    __shared__ float sR[64 * 36];     // 9 KB
    int tid = threadIdx.x;
    int mode = A.mode;
    if (mode != 5) {
#pragma unroll
        for (int k = 0; k < 4; k++) { int i = k * 256 + tid; sW[i] = P.W[i]; }
    }

    int c = tid & 3;
    int nl = tid >> 2;
    int n = blk * 64 + nl;        // SORTED position (bin-local sort)
    bool active = n < NN;
    float dn = 0.f;
    float4 r40 = make_float4(0.f, 0.f, 0.f, 0.f);
    float4 r41 = make_float4(0.f, 0.f, 0.f, 0.f);
    float4 bs0 = make_float4(0.f, 0.f, 0.f, 0.f);
    float4 bs1 = make_float4(0.f, 0.f, 0.f, 0.f);

    if (active) {
        int e = P.row_ptr[n], e1 = P.row_ptr[n + 1];   // multiples of 8
        const uint4* xwq = P.xw_in + c;
        const uint4* cw4 = (const uint4*)P.cw;
        int q = e >> 3, qe = e1 >> 3;
        float4 sum0 = make_float4(0.f, 0.f, 0.f, 0.f);
        float4 sum1 = make_float4(0.f, 0.f, 0.f, 0.f);
        uint4 ra;
        if (q < qe) ra = cw4[q];
        while (q < qe) {
            unsigned s0 = ra.x & 0xffffu, s1 = ra.x >> 16;
            unsigned s2 = ra.y & 0xffffu, s3 = ra.y >> 16;
            unsigned s4 = ra.z & 0xffffu, s5 = ra.z >> 16;
            unsigned s6 = ra.w & 0xffffu, s7 = ra.w >> 16;
            uint4 u0 = xwq[(size_t)s0 * 4];
            uint4 u1 = xwq[(size_t)s1 * 4];
            uint4 u2 = xwq[(size_t)s2 * 4];
            uint4 u3 = xwq[(size_t)s3 * 4];
            uint4 u4 = xwq[(size_t)s4 * 4];
            uint4 u5 = xwq[(size_t)s5 * 4];
            uint4 u6 = xwq[(size_t)s6 * 4];
            uint4 u7 = xwq[(size_t)s7 * 4];
            int qn = q + 1;
            uint4 nx;
            if (qn < qe) nx = cw4[qn];
            EDGE_ADD(u0) EDGE_ADD(u1) EDGE_ADD(u2) EDGE_ADD(u3)
            EDGE_ADD(u4) EDGE_ADD(u5) EDGE_ADD(u6) EDGE_ADD(u7)
            if (qn < qe) ra = nx;
            q = qn;
        }
        dn = P.dis[n];
        uint4 un = xwq[(size_t)n * 4];
        float4 vn0 = bf4_to_f4(make_uint2(un.x, un.y));
        float4 vn1 = bf4_to_f4(make_uint2(un.z, un.w));
        float4 bb0 = *(const float4*)&P.b[c * 8];
        float4 bb1 = *(const float4*)&P.b[c * 8 + 4];
        sum0.x = fmaf(dn, sum0.x + vn0.x, bb0.x);
        sum0.y = fmaf(dn, sum0.y + vn0.y, bb0.y);
        sum0.z = fmaf(dn, sum0.z + vn0.z, bb0.z);
        sum0.w = fmaf(dn, sum0.w + vn0.w, bb0.w);
        sum1.x = fmaf(dn, sum1.x + vn1.x, bb1.x);
        sum1.y = fmaf(dn, sum1.y + vn1.y, bb1.y);
        sum1.z = fmaf(dn, sum1.z + vn1.z, bb1.z);
        sum1.w = fmaf(dn, sum1.w + vn1.w, bb1.w);
        float4 w40 = *(const float4*)&P.wt[c * 8];
        float4 w41 = *(const float4*)&P.wt[c * 8 + 4];
        float t = A.t;
        float4 kv0, kv1;
        kv0.x = fmaxf(sum0.x, 0.f) / (1.f + __expf(-t * w40.x));
        kv0.y = fmaxf(sum0.y, 0.f) / (1.f + __expf(-t * w40.y));
        kv0.z = fmaxf(sum0.z, 0.f) / (1.f + __expf(-t * w40.z));
        kv0.w = fmaxf(sum0.w, 0.f) / (1.f + __expf(-t * w40.w));
        kv1.x = fmaxf(sum1.x, 0.f) / (1.f + __expf(-t * w41.x));
        kv1.y = fmaxf(sum1.y, 0.f) / (1.f + __expf(-t * w41.y));
        kv1.z = fmaxf(sum1.z, 0.f) / (1.f + __expf(-t * w41.z));
        kv1.w = fmaxf(sum1.w, 0.f) / (1.f + __expf(-t * w41.w));

        uint4* accp = P.acc + (size_t)n * 4 + c;
        if (mode == 1) {
            *accp = pack_bf8(kv0, kv1);
            r40 = kv0; r41 = kv1;
            bs0 = vn0; bs1 = vn1;
        } else if (mode <= 3) {
            uint4 ao = *accp;
            float4 a0 = bf4_to_f4(make_uint2(ao.x, ao.y));
            float4 a1 = bf4_to_f4(make_uint2(ao.z, ao.w));
            a0.x = fmaf(2.f, kv0.x, a0.x); a0.y = fmaf(2.f, kv0.y, a0.y);
            a0.z = fmaf(2.f, kv0.z, a0.z); a0.w = fmaf(2.f, kv0.w, a0.w);
            a1.x = fmaf(2.f, kv1.x, a1.x); a1.y = fmaf(2.f, kv1.y, a1.y);
            a1.z = fmaf(2.f, kv1.z, a1.z); a1.w = fmaf(2.f, kv1.w, a1.w);
            *accp = pack_bf8(a0, a1);
            r40 = kv0; r41 = kv1;
            uint4 ub = P.xw_base[(size_t)n * 4 + c];
            bs0 = bf4_to_f4(make_uint2(ub.x, ub.y));
            bs1 = bf4_to_f4(make_uint2(ub.z, ub.w));
        } else {
            uint4 ao = *accp;
            float4 f0 = bf4_to_f4(make_uint2(ao.x, ao.y));
            float4 f1 = bf4_to_f4(make_uint2(ao.z, ao.w));
            f0.x += kv0.x; f0.y += kv0.y; f0.z += kv0.z; f0.w += kv0.w;
            f1.x += kv1.x; f1.y += kv1.y; f1.z += kv1.z; f1.w += kv1.w;
            int id = P.perm[n];
            size_t o = (size_t)id * DIM + c * 8;
            float4 xc0 = *(const float4*)&P.x_cur[o];
            float4 xc1 = *(const float4*)&P.x_cur[o + 4];
            float4 xn0, xn1;
            xn0.x = fmaf(HS / 6.f, f0.x, xc0.x); xn0.y = fmaf(HS / 6.f, f0.y, xc0.y);
            xn0.z = fmaf(HS / 6.f, f0.z, xc0.z); xn0.w = fmaf(HS / 6.f, f0.w, xc0.w);
            xn1.x = fmaf(HS / 6.f, f1.x, xc1.x); xn1.y = fmaf(HS / 6.f, f1.y, xc1.y);
            xn1.z = fmaf(HS / 6.f, f1.z, xc1.z); xn1.w = fmaf(HS / 6.f, f1.w, xc1.w);
            if (mode == 4) {
                *(float4*)&P.x_cur[o] = xn0;
                *(float4*)&P.x_cur[o + 4] = xn1;
                r40 = f0; r41 = f1;
                uint4 ub = P.xw_base[(size_t)n * 4 + c];
                bs0 = bf4_to_f4(make_uint2(ub.x, ub.y));
                bs1 = bf4_to_f4(make_uint2(ub.z, ub.w));
            } else {
                *(float4*)&P.zout[o] = xn0;
                *(float4*)&P.zout[o + 4] = xn1;
            }
        }
    }

    if (mode == 5) return;

    *(float4*)&sR[nl * 36 + c * 8] = r40;
    *(float4*)&sR[nl * 36 + c * 8 + 4] = r41;
    __syncthreads();
    if (active) {
        float4 y0 = make_float4(0.f, 0.f, 0.f, 0.f);
        float4 y1 = make_float4(0.f, 0.f, 0.f, 0.f);
        const float* row = &sR[nl * 36];
#pragma unroll
        for (int i = 0; i < DIM; i++) {
            float sv = row[i];
            float4 wA = *(const float4*)&sW[i * DIM + c * 8];
            float4 wB = *(const float4*)&sW[i * DIM + c * 8 + 4];
            y0.x = fmaf(sv, wA.x, y0.x); y0.y = fmaf(sv, wA.y, y0.y);
            y0.z = fmaf(sv, wA.z, y0.z); y0.w = fmaf(sv, wA.w, y0.w);
            y1.x = fmaf(sv, wB.x, y1.x); y1.y = fmaf(sv, wB.y, y1.y);
            y1.z = fmaf(sv, wB.z, y1.z); y1.w = fmaf(sv, wB.w, y1.w);
        }
        float sd = A.stage_coef * dn;
        y0.x = fmaf(sd, y0.x, bs0.x); y0.y = fmaf(sd, y0.y, bs0.y);
        y0.z = fmaf(sd, y0.z, bs0.z); y0.w = fmaf(sd, y0.w, bs0.w);
        y1.x = fmaf(sd, y1.x, bs1.x); y1.y = fmaf(sd, y1.y, bs1.y);
        y1.z = fmaf(sd, y1.z, bs1.z); y1.w = fmaf(sd, y1.w, bs1.w);
        P.xw_out[(size_t)n * 4 + c] = pack_bf8(y0, y1);
    }
}

// ---------------- host ----------------

extern "C" void kernel_launch(void* const* d_in, const int* in_sizes, int n_in,
                              void* d_out, int out_size, void* d_ws, size_t ws_size,
                              hipStream_t stream) {
    const float* x   = (const float*)d_in[0];
    const int* epos  = (const int*)d_in[1];
    const int* eneg  = (const int*)d_in[2];
    const float* Wp  = (const float*)d_in[3];
    const float* bp  = (const float*)d_in[4];
    const float* wtp = (const float*)d_in[5];
    const float* Wn  = (const float*)d_in[6];
    const float* bn  = (const float*)d_in[7];
    const float* wtn = (const float*)d_in[8];
    float* out = (float*)d_out;

    char* ws = (char*)d_ws;
    size_t off = 0;
    auto alloc = [&](size_t bytes) -> void* {
        void* p = ws + off;
        off += (bytes + 255) & ~(size_t)255;
        return p;
    };

    struct Sign {
        int *row_ptr, *cnt, *perm, *pos, *gcnt, *btot;
        unsigned* gstage;
        float* dis;
        ushort_t* cw;
        float* x_cur;
        uint4* acc;
        uint4* xwbuf[3];
        const int *src, *dst;
        const float *W, *b, *wt;
        float* zout;
    } S[2];

    const size_t CWCAP = (size_t)NE + 8u * NN;
    int* bint    = (int*)alloc(2 * NBIN * sizeof(int));
    int* binbase = (int*)alloc(2 * NBIN * sizeof(int));

    for (int s = 0; s < 2; s++) {
        S[s].row_ptr  = (int*)alloc((NN + 1) * sizeof(int));
        S[s].cnt      = (int*)alloc(NN * sizeof(int));
        S[s].perm     = (int*)alloc(NN * sizeof(int));
        S[s].pos      = (int*)alloc(NN * sizeof(int));
        S[s].gcnt     = (int*)alloc((size_t)AB * NBIN * sizeof(int));
        S[s].btot     = (int*)alloc(NBIN * sizeof(int));
        S[s].gstage   = (unsigned*)alloc((size_t)NE * sizeof(unsigned));
        S[s].dis      = (float*)alloc(NN * sizeof(float));
        S[s].cw       = (ushort_t*)alloc(CWCAP * sizeof(ushort_t));
        S[s].x_cur    = (float*)alloc((size_t)NN * DIM * sizeof(float));
        S[s].acc      = (uint4*)alloc((size_t)NN * DIM * 2);
        S[s].xwbuf[0] = (uint4*)alloc((size_t)(NN + 1) * DIM * 2);
        S[s].xwbuf[1] = (uint4*)alloc((size_t)(NN + 1) * DIM * 2);
        S[s].xwbuf[2] = (uint4*)alloc((size_t)(NN + 1) * DIM * 2);
    }
    S[0].src = epos; S[0].dst = epos + NE; S[0].W = Wp; S[0].b = bp; S[0].wt = wtp;
    S[0].zout = out;
    S[1].src = eneg; S[1].dst = eneg + NE; S[1].W = Wn; S[1].b = bn; S[1].wt = wtn;
    S[1].zout = out + (size_t)NN * DIM;

    // ---- setup: radix CSR build, bin-local sort (no hist, no global atomics) ----
    k_countA<<<2 * AB, 512, 0, stream>>>(S[0].dst, S[1].dst, S[0].gcnt, S[1].gcnt);
    k_scanM1<<<2 * NBIN, 512, 0, stream>>>(S[0].gcnt, S[1].gcnt, bint);
    k_scanM2<<<1, 256, 0, stream>>>(bint, binbase);
    k_scatA<<<2 * AB, 512, 0, stream>>>(S[0].src, S[0].dst, S[1].src, S[1].dst,
                                        S[0].gcnt, S[1].gcnt, binbase,
                                        S[0].gstage, S[1].gstage);
    k_degB<<<2 * NBIN, 256, 0, stream>>>(S[0].gstage, S[1].gstage, bint, binbase,
                                         S[0].cnt, S[1].cnt, S[0].pos, S[1].pos,
                                         S[0].perm, S[1].perm, S[0].dis, S[1].dis,
                                         S[0].row_ptr, S[1].row_ptr,
                                         S[0].btot, S[1].btot);
    k_binscan<<<2, 256, 0, stream>>>(S[0].btot, S[1].btot);
    k_rowfix<<<2 * NNB, 256, 0, stream>>>(S[0].row_ptr, S[1].row_ptr,
                                          S[0].btot, S[1].btot);
    k_scatB<<<2 * NBIN, 512, 0, stream>>>(S[0].row_ptr, S[1].row_ptr,
                                          S[0].gstage, S[1].gstage,
                                          bint, binbase, S[0].pos, S[1].pos,
                                          S[0].cw, S[1].cw);

    // ---- per-run state init: zero rows, T_base, x_cur = x ----
    ZArgs Z;
    for (int s = 0; s < 2; s++)
        for (int k = 0; k < 3; k++) Z.p[s * 3 + k] = (unsigned*)S[s].xwbuf[k];
    k_zrow<<<1, 96, 0, stream>>>(Z);
    for (int s = 0; s < 2; s++)
        k_matmul<<<cdiv(NN, 32), 256, 0, stream>>>(x, S[s].W, S[s].cnt, S[s].pos,
                                                   (uint2*)S[s].xwbuf[0], S[s].x_cur);

    // ---- RK4 main loop: 4 fused stages per step, both signs per dispatch ----
    for (int st = 0; st < 10; st++) {
        float tb = HS * (float)st;
        struct Ph { float t, sc; int mode, in, out; } ph[4] = {
            { tb,             HS * 0.5f, 1,              0, 1 },
            { tb + HS * 0.5f, HS * 0.5f, 2,              1, 2 },
            { tb + HS * 0.5f, HS,        3,              2, 1 },
            { tb + HS,        HS / 6.f,  st == 9 ? 5 : 4, 1, 0 },
        };
        for (int p = 0; p < 4; p++) {
            StageArgs A;
            for (int s = 0; s < 2; s++) {
                A.s[s].row_ptr = S[s].row_ptr;
                A.s[s].cw      = S[s].cw;
                A.s[s].dis     = S[s].dis;
                A.s[s].perm    = S[s].perm;
                A.s[s].xw_in   = S[s].xwbuf[ph[p].in];
                A.s[s].xw_out  = S[s].xwbuf[ph[p].out];
                A.s[s].xw_base = S[s].xwbuf[0];
                A.s[s].acc     = S[s].acc;
                A.s[s].x_cur   = S[s].x_cur;
                A.s[s].W       = S[s].W;
                A.s[s].b       = S[s].b;
                A.s[s].wt      = S[s].wt;
                A.s[s].zout    = S[s].zout;
            }
            A.t = ph[p].t; A.stage_coef = ph[p].sc; A.mode = ph[p].mode;
            k_stage<<<2 * NBPS, 256, 0, stream>>>(A);
        }
    }
}

// Round 12
// 1249.975 us; speedup vs baseline: 1.1113x; 1.1113x over previous
//
#include <hip/hip_runtime.h>

#define NN 50000
#define NE 1600000
#define DIM 32
#define HS 0.1f
#define NBPS 784       // 4 slices x 196 bins (heavy-first slice-major stage map)
#define NNB 196        // cdiv(NN, 256)
#define SBIN 256       // nodes per bin (orig-id and sorted-pos space coincide per bin)
#define NBIN 196       // cdiv(NN, SBIN)
#define AB 391         // cdiv(NE, 4096) phase-A blocks per sign
#define WCAP 22528     // scatB LDS window capacity (ushorts, 45KB)

static inline int cdiv(int a, int b) { return (a + b - 1) / b; }

typedef unsigned short ushort_t;

// NO non-temporal hints anywhere (r1/r2 -480us, r8 -250us: line-sharing).
// NO deep global-atomic chains (r3 377us, r6 93us, r10 144us hist).
// Stage blocks are SLICE-MAJOR (heavy ranks first): r11's bin-major order put
// heavy blocks at the launch tail and cost ~3us/dispatch in stragglers.

// bf16x4 (uint2) -> float4
__device__ __forceinline__ float4 bf4_to_f4(uint2 u) {
    float4 v;
    v.x = __uint_as_float(u.x << 16);
    v.y = __uint_as_float(u.x & 0xffff0000u);
    v.z = __uint_as_float(u.y << 16);
    v.w = __uint_as_float(u.y & 0xffff0000u);
    return v;
}
__device__ __forceinline__ unsigned pack_bf2(float a, float b) {
    unsigned ua = __float_as_uint(a);
    ua = (ua + 0x7fffu + ((ua >> 16) & 1u)) >> 16;
    unsigned ub = __float_as_uint(b);
    ub = (ub + 0x7fffu + ((ub >> 16) & 1u)) & 0xffff0000u;
    return ua | ub;
}
__device__ __forceinline__ uint4 pack_bf8(float4 a, float4 b) {
    return make_uint4(pack_bf2(a.x, a.y), pack_bf2(a.z, a.w),
                      pack_bf2(b.x, b.y), pack_bf2(b.z, b.w));
}

// ---------------- radix CSR build (orig-space bins; no global atomics) ----------------

// count matrix gcnt[blk][bin]: edges per (phase-A block, dst-bin), bin = dst>>8
__global__ __launch_bounds__(512) void k_countA(const int* __restrict__ d0,
                        const int* __restrict__ d1,
                        int* __restrict__ gc0, int* __restrict__ gc1) {
    __shared__ int lc[NBIN];
    int b = blockIdx.x, sg = b & 1, blk = b >> 1;
    int t = threadIdx.x;
    if (t < NBIN) lc[t] = 0;
    __syncthreads();
    const int* dst = sg ? d1 : d0;
#pragma unroll
    for (int i = 0; i < 8; i++) {
        int e = blk * 4096 + i * 512 + t;
        if (e < NE) atomicAdd(&lc[dst[e] >> 8], 1);
    }
    __syncthreads();
    int* gc = sg ? gc1 : gc0;
    if (t < NBIN) gc[blk * NBIN + t] = lc[t];
}

// per-bin exclusive scan over blocks + bin totals
__global__ __launch_bounds__(512) void k_scanM1(int* __restrict__ gc0,
                                                int* __restrict__ gc1,
                                                int* __restrict__ bint) {
    __shared__ int s[512];
    int b = blockIdx.x, sg = b & 1, bin = b >> 1;
    int* gc = sg ? gc1 : gc0;
    int t = threadIdx.x;
    int v = (t < AB) ? gc[t * NBIN + bin] : 0;
    s[t] = v;
    __syncthreads();
    for (int off = 1; off < 512; off <<= 1) {
        int a = (t >= off) ? s[t - off] : 0;
        __syncthreads();
        s[t] += a;
        __syncthreads();
    }
    if (t < AB) gc[t * NBIN + bin] = s[t] - v;
    if (t == AB - 1) bint[sg * NBIN + bin] = s[t];
}

// exclusive scan of bin totals -> staging bases
__global__ __launch_bounds__(256) void k_scanM2(const int* __restrict__ bint,
                                                int* __restrict__ binbase) {
    __shared__ int s[256];
    int t = threadIdx.x;
    for (int sg = 0; sg < 2; sg++) {
        int v = (t < NBIN) ? bint[sg * NBIN + t] : 0;
        s[t] = v;
        __syncthreads();
        for (int off = 1; off < 256; off <<= 1) {
            int a = (t >= off) ? s[t - off] : 0;
            __syncthreads();
            s[t] += a;
            __syncthreads();
        }
        if (t < NBIN) binbase[sg * NBIN + t] = s[t] - v;
        __syncthreads();
    }
}

// bin-group records (src<<8 | dst&255) into staging at precomputed offsets
__global__ __launch_bounds__(512) void k_scatA(const int* __restrict__ s0s,
                        const int* __restrict__ s0d,
                        const int* __restrict__ s1s, const int* __restrict__ s1d,
                        const int* __restrict__ gc0, const int* __restrict__ gc1,
                        const int* __restrict__ binbase,
                        unsigned* __restrict__ gst0, unsigned* __restrict__ gst1) {
    __shared__ int lc[NBIN];
    __shared__ int lst[NBIN];
    __shared__ int gch[NBIN];
    __shared__ unsigned stag[4096];
    __shared__ ushort_t bos[4096];
    int b = blockIdx.x, sg = b & 1, blk = b >> 1;
    int t = threadIdx.x;
    if (t < NBIN) lc[t] = 0;
    __syncthreads();
    const int* src = sg ? s1s : s0s;
    const int* dst = sg ? s1d : s0d;
    const int* gc  = sg ? gc1 : gc0;
    unsigned er[8]; int ebin[8]; int erk[8];
#pragma unroll
    for (int i = 0; i < 8; i++) {
        int e = blk * 4096 + i * 512 + t;
        ebin[i] = -1;
        if (e < NE) {
            int d = dst[e];
            int bin = d >> 8;
            ebin[i] = bin;
            er[i] = ((unsigned)src[e] << 8) | (unsigned)(d & 255);
            erk[i] = atomicAdd(&lc[bin], 1);
        }
    }
    __syncthreads();
    if (t < NBIN) lst[t] = lc[t];
    __syncthreads();
    for (int off = 1; off < NBIN; off <<= 1) {
        int a = (t >= off && t < NBIN) ? lst[t - off] : 0;
        __syncthreads();
        if (t < NBIN) lst[t] += a;
        __syncthreads();
    }
    if (t < NBIN) {
        lst[t] -= lc[t];
        gch[t] = binbase[sg * NBIN + t] + gc[blk * NBIN + t];
    }
    __syncthreads();
#pragma unroll
    for (int i = 0; i < 8; i++) {
        if (ebin[i] >= 0) {
            int slot = lst[ebin[i]] + erk[i];
            stag[slot] = er[i];
            bos[slot] = (ushort_t)ebin[i];
        }
    }
    __syncthreads();
    unsigned* gst = sg ? gst1 : gst0;
    int tot = (blk * 4096 + 4096 <= NE) ? 4096 : (NE - blk * 4096);
#pragma unroll
    for (int i = 0; i < 8; i++) {
        int slot = i * 512 + t;
        if (slot < tot) {
            int bin = bos[slot];
            gst[gch[bin] + (slot - lst[bin])] = stag[slot];
        }
    }
}

// per-bin: degrees via LDS counting, bin-local descending counting-sort ->
// cnt/pos/perm/dis, within-bin padded row prefix
__global__ __launch_bounds__(256) void k_degB(
        const unsigned* __restrict__ gst0, const unsigned* __restrict__ gst1,
        const int* __restrict__ bint, const int* __restrict__ binbase,
        int* __restrict__ c0, int* __restrict__ c1,
        int* __restrict__ pos0, int* __restrict__ pos1,
        int* __restrict__ perm0, int* __restrict__ perm1,
        float* __restrict__ q0, float* __restrict__ q1,
        int* __restrict__ r0, int* __restrict__ r1,
        int* __restrict__ bt0, int* __restrict__ bt1) {
    __shared__ int deg[SBIN];
    __shared__ int dh[256];
    __shared__ int spd[SBIN];
    __shared__ int s[256];
    int b = blockIdx.x, sg = b & 1, bin = b >> 1;
    int t = threadIdx.x;
    const unsigned* gst = sg ? gst1 : gst0;
    int p0 = bin * SBIN;
    int nn = NN - p0; if (nn > SBIN) nn = SBIN;
    deg[t] = 0; dh[t] = 0;
    __syncthreads();
    int cntr = bint[sg * NBIN + bin];
    int base = binbase[sg * NBIN + bin];
    for (int i = t; i < cntr; i += 256)
        atomicAdd(&deg[gst[base + i] & 255u], 1);
    __syncthreads();
    int d = 0, dc = 0;
    if (t < nn) {
        d = deg[t];
        dc = d > 255 ? 255 : d;
        atomicAdd(&dh[dc], 1);
    }
    __syncthreads();
    s[t] = dh[255 - t];
    __syncthreads();
    for (int off = 1; off < 256; off <<= 1) {
        int a = (t >= off) ? s[t - off] : 0;
        __syncthreads();
        s[t] += a;
        __syncthreads();
    }
    int ex = (t == 0) ? 0 : s[t - 1];
    __syncthreads();
    dh[255 - t] = ex;          // dh[d] = first rank for degree d (descending)
    __syncthreads();
    if (t < nn) {
        int r = atomicAdd(&dh[dc], 1);   // unique rank within bin
        int* cnt = sg ? c1 : c0;
        int* pos = sg ? pos1 : pos0;
        int* perm = sg ? perm1 : perm0;
        float* dq = sg ? q1 : q0;
        cnt[p0 + t] = d;
        pos[p0 + t] = p0 + r;
        perm[p0 + r] = p0 + t;
        dq[p0 + r] = rsqrtf((float)d + 1.0f);
        spd[r] = (d + 7) & ~7;
    }
    __syncthreads();
    int v = (t < nn) ? spd[t] : 0;
    s[t] = v;
    __syncthreads();
    for (int off = 1; off < 256; off <<= 1) {
        int a = (t >= off) ? s[t - off] : 0;
        __syncthreads();
        s[t] += a;
        __syncthreads();
    }
    int* rp = sg ? r1 : r0;
    int* bt = sg ? bt1 : bt0;
    if (t < nn) rp[p0 + t + 1] = s[t];
    if (t == nn - 1) bt[bin] = s[t];
}

// exclusive scan of bin CSR totals (in place: bt becomes bin start)
__global__ __launch_bounds__(256) void k_binscan(int* __restrict__ bt0,
                                                 int* __restrict__ bt1) {
    __shared__ int s[256];
    int sg = blockIdx.x, t = threadIdx.x;
    int* bt = sg ? bt1 : bt0;
    int v = (t < NBIN) ? bt[t] : 0;
    s[t] = v;
    __syncthreads();
    for (int off = 1; off < 256; off <<= 1) {
        int a = (t >= off) ? s[t - off] : 0;
        __syncthreads();
        s[t] += a;
        __syncthreads();
    }
    if (t < NBIN) bt[t] = s[t] - v;
}

// row_ptr absolute: add bin starts
__global__ void k_rowfix(int* __restrict__ r0, int* __restrict__ r1,
                         const int* __restrict__ bt0, const int* __restrict__ bt1) {
    int b = blockIdx.x, sg = b & 1;
    int g = (b >> 1) * 256 + (int)threadIdx.x;
    int* rp = sg ? r1 : r0;
    const int* bt = sg ? bt1 : bt0;
    if (g < NN) rp[g + 1] += bt[g >> 8];
    if (g == 0) rp[0] = 0;
}

// per-bin LDS-window scatter + pad, fully-coalesced uint4 write-out
__global__ __launch_bounds__(512) void k_scatB(const int* __restrict__ r0,
                        const int* __restrict__ r1,
                        const unsigned* __restrict__ gst0,
                        const unsigned* __restrict__ gst1,
                        const int* __restrict__ bint, const int* __restrict__ binbase,
                        const int* __restrict__ pos0, const int* __restrict__ pos1,
                        ushort_t* __restrict__ w0, ushort_t* __restrict__ w1) {
    __shared__ uint4 winq[WCAP / 8];
    __shared__ int lrp[SBIN + 1];
    __shared__ int lfill[SBIN];
    __shared__ int lpos[SBIN];
    ushort_t* win = (ushort_t*)winq;
    int b = blockIdx.x, sg = b & 1, bin = b >> 1;
    int t = threadIdx.x;
    const int* rp = sg ? r1 : r0;
    const unsigned* gst = sg ? gst1 : gst0;
    const int* pos = sg ? pos1 : pos0;
    ushort_t* cw = sg ? w1 : w0;
    int p0 = bin * SBIN;
    int nn = NN - p0; if (nn > SBIN) nn = SBIN;
    if (t <= nn) lrp[t] = rp[p0 + t];
    if (t < nn) { lfill[t] = 0; lpos[t] = pos[p0 + t] - p0; }
    __syncthreads();
    int wb = lrp[0];
    int wl = lrp[nn] - wb;
    int cnt = bint[sg * NBIN + bin];
    int base = binbase[sg * NBIN + bin];
    if (wl <= WCAP) {
        for (int i = t; i < cnt; i += 512) {
            unsigned e = gst[base + i];
            int rl = lpos[e & 255u];
            int ps = pos[e >> 8];
            int ofs = atomicAdd(&lfill[rl], 1);
            win[lrp[rl] - wb + ofs] = (ushort_t)ps;
        }
        __syncthreads();
        for (int ln = t; ln < nn; ln += 512) {
            int e0 = lrp[ln] - wb + lfill[ln], e1 = lrp[ln + 1] - wb;
            for (int j = e0; j < e1; j++) win[j] = (ushort_t)NN;
        }
        __syncthreads();
        uint4* dst4 = (uint4*)(cw + wb);   // wb multiple of 8 -> 16B aligned
        int nq = wl >> 3;
        for (int i = t; i < nq; i += 512) dst4[i] = winq[i];
    } else {
        for (int i = t; i < cnt; i += 512) {
            unsigned e = gst[base + i];
            int rl = lpos[e & 255u];
            int ps = pos[e >> 8];
            int ofs = atomicAdd(&lfill[rl], 1);
            cw[lrp[rl] + ofs] = (ushort_t)ps;
        }
        __syncthreads();
        for (int ln = t; ln < nn; ln += 512) {
            int e0 = lrp[ln] + lfill[ln], e1 = lrp[ln + 1];
            for (int j = e0; j < e1; j++) cw[j] = (ushort_t)NN;
        }
    }
}

// zero row NN of all six table buffers (16 uints each)
struct ZArgs { unsigned* p[6]; };
__global__ void k_zrow(ZArgs z) {
    int t = threadIdx.x;
    if (t < 96) z.p[t >> 4][(size_t)NN * 16 + (t & 15)] = 0u;
}

// T_base[pos[n]] = bf16(dis[n]*(x@W)[n]), x_cur = x
__global__ __launch_bounds__(256) void k_matmul(const float* __restrict__ src,
                                                const float* __restrict__ W,
                                                const int* __restrict__ cnt,
                                                const int* __restrict__ pos,
                                                uint2* __restrict__ xw,
                                                float* __restrict__ copy_out) {
    __shared__ float sW[DIM * DIM];
    __shared__ float sX[32 * 33];
    int t = threadIdx.x;
#pragma unroll
    for (int k = 0; k < 4; k++) { int i = k * 256 + t; sW[i] = W[i]; }
    size_t base = (size_t)blockIdx.x * 32 * DIM;
#pragma unroll
    for (int k = 0; k < 4; k++) {
        int i = k * 256 + t;
        size_t g = base + i;
        float v = 0.f;
        if (g < (size_t)NN * DIM) {
            v = src[g];
            copy_out[g] = v;
        }
        sX[(i >> 5) * 33 + (i & 31)] = v;
    }
    __syncthreads();
    int r = t >> 3, oct = t & 7;
    int row = blockIdx.x * 32 + r;
    if (row >= NN) return;
    float a0 = 0.f, a1 = 0.f, a2 = 0.f, a3 = 0.f;
    const float* xr = &sX[r * 33];
#pragma unroll
    for (int i = 0; i < DIM; i++) {
        float xv = xr[i];
        const float* wr = &sW[i * DIM + oct * 4];
        a0 = fmaf(xv, wr[0], a0);
        a1 = fmaf(xv, wr[1], a1);
        a2 = fmaf(xv, wr[2], a2);
        a3 = fmaf(xv, wr[3], a3);
    }
    float dn = rsqrtf((float)cnt[row] + 1.0f);
    a0 *= dn; a1 *= dn; a2 *= dn; a3 *= dn;
    xw[(size_t)pos[row] * 8 + oct] = make_uint2(pack_bf2(a0, a1), pack_bf2(a2, a3));
}

// ---------------- fused stage kernel (bin-local degree-sorted space) ----------------
// Block map is SLICE-MAJOR: blocks 0..NBIN-1 cover every bin's heaviest 64
// ranks and launch first; the lightest ranks launch last (clean tail).

struct SignP {
    const int* row_ptr; const ushort_t* cw; const float* dis;
    const int* perm;
    const uint4* xw_in; uint4* xw_out; const uint4* xw_base;
    uint4* acc;                      // bf16, row stride 4 uint4
    float* x_cur;
    const float* W; const float* b; const float* wt;
    float* zout;
};
struct StageArgs { SignP s[2]; float t, stage_coef; int mode; };

#define EDGE_ADD(u)                                                     \
    {                                                                   \
        float4 vA = bf4_to_f4(make_uint2((u).x, (u).y));                \
        float4 vB = bf4_to_f4(make_uint2((u).z, (u).w));                \
        sum0.x += vA.x; sum0.y += vA.y; sum0.z += vA.z; sum0.w += vA.w; \
        sum1.x += vB.x; sum1.y += vB.y; sum1.z += vB.z; sum1.w += vB.w; \
    }

__global__ __launch_bounds__(256) void k_stage(StageArgs A) {
    int sg = blockIdx.x & 1;
    int blk = blockIdx.x >> 1;
    SignP P = A.s[sg];

    __shared__ float sW[DIM * DIM];   // 4 KB
    __shared__ float sR[64 * 36];     // 9 KB
    int tid = threadIdx.x;
    int mode = A.mode;
    if (mode != 5) {
#pragma unroll
        for (int k = 0; k < 4; k++) { int i = k * 256 + tid; sW[i] = P.W[i]; }
    }

    int c = tid & 3;
    int nl = tid >> 2;
    int slice = blk / NBIN;            // 0..3 (rank quartile, heavy first)
    int bin   = blk - slice * NBIN;
    int n = bin * SBIN + slice * 64 + nl;   // SORTED position
    bool active = n < NN;
    float dn = 0.f;
    float4 r40 = make_float4(0.f, 0.f, 0.f, 0.f);
    float4 r41 = make_float4(0.f, 0.f, 0.f, 0.f);
    float4 bs0 = make_float4(0.f, 0.f, 0.f, 0.f);
    float4 bs1 = make_float4(0.f, 0.f, 0.f, 0.f);

    if (active) {
        int e = P.row_ptr[n], e1 = P.row_ptr[n + 1];   // multiples of 8
        const uint4* xwq = P.xw_in + c;
        const uint4* cw4 = (const uint4*)P.cw;
        int q = e >> 3, qe = e1 >> 3;
        float4 sum0 = make_float4(0.f, 0.f, 0.f, 0.f);
        float4 sum1 = make_float4(0.f, 0.f, 0.f, 0.f);
        uint4 ra;
        if (q < qe) ra = cw4[q];
        while (q < qe) {
            unsigned s0 = ra.x & 0xffffu, s1 = ra.x >> 16;
            unsigned s2 = ra.y & 0xffffu, s3 = ra.y >> 16;
            unsigned s4 = ra.z & 0xffffu, s5 = ra.z >> 16;
            unsigned s6 = ra.w & 0xffffu, s7 = ra.w >> 16;
            uint4 u0 = xwq[(size_t)s0 * 4];
            uint4 u1 = xwq[(size_t)s1 * 4];
            uint4 u2 = xwq[(size_t)s2 * 4];
            uint4 u3 = xwq[(size_t)s3 * 4];
            uint4 u4 = xwq[(size_t)s4 * 4];
            uint4 u5 = xwq[(size_t)s5 * 4];
            uint4 u6 = xwq[(size_t)s6 * 4];
            uint4 u7 = xwq[(size_t)s7 * 4];
            int qn = q + 1;
            uint4 nx;
            if (qn < qe) nx = cw4[qn];
            EDGE_ADD(u0) EDGE_ADD(u1) EDGE_ADD(u2) EDGE_ADD(u3)
            EDGE_ADD(u4) EDGE_ADD(u5) EDGE_ADD(u6) EDGE_ADD(u7)
            if (qn < qe) ra = nx;
            q = qn;
        }
        dn = P.dis[n];
        uint4 un = xwq[(size_t)n * 4];
        float4 vn0 = bf4_to_f4(make_uint2(un.x, un.y));
        float4 vn1 = bf4_to_f4(make_uint2(un.z, un.w));
        float4 bb0 = *(const float4*)&P.b[c * 8];
        float4 bb1 = *(const float4*)&P.b[c * 8 + 4];
        sum0.x = fmaf(dn, sum0.x + vn0.x, bb0.x);
        sum0.y = fmaf(dn, sum0.y + vn0.y, bb0.y);
        sum0.z = fmaf(dn, sum0.z + vn0.z, bb0.z);
        sum0.w = fmaf(dn, sum0.w + vn0.w, bb0.w);
        sum1.x = fmaf(dn, sum1.x + vn1.x, bb1.x);
        sum1.y = fmaf(dn, sum1.y + vn1.y, bb1.y);
        sum1.z = fmaf(dn, sum1.z + vn1.z, bb1.z);
        sum1.w = fmaf(dn, sum1.w + vn1.w, bb1.w);
        float4 w40 = *(const float4*)&P.wt[c * 8];
        float4 w41 = *(const float4*)&P.wt[c * 8 + 4];
        float t = A.t;
        float4 kv0, kv1;
        kv0.x = fmaxf(sum0.x, 0.f) / (1.f + __expf(-t * w40.x));
        kv0.y = fmaxf(sum0.y, 0.f) / (1.f + __expf(-t * w40.y));
        kv0.z = fmaxf(sum0.z, 0.f) / (1.f + __expf(-t * w40.z));
        kv0.w = fmaxf(sum0.w, 0.f) / (1.f + __expf(-t * w40.w));
        kv1.x = fmaxf(sum1.x, 0.f) / (1.f + __expf(-t * w41.x));
        kv1.y = fmaxf(sum1.y, 0.f) / (1.f + __expf(-t * w41.y));
        kv1.z = fmaxf(sum1.z, 0.f) / (1.f + __expf(-t * w41.z));
        kv1.w = fmaxf(sum1.w, 0.f) / (1.f + __expf(-t * w41.w));

        uint4* accp = P.acc + (size_t)n * 4 + c;
        if (mode == 1) {
            *accp = pack_bf8(kv0, kv1);
            r40 = kv0; r41 = kv1;
            bs0 = vn0; bs1 = vn1;
        } else if (mode <= 3) {
            uint4 ao = *accp;
            float4 a0 = bf4_to_f4(make_uint2(ao.x, ao.y));
            float4 a1 = bf4_to_f4(make_uint2(ao.z, ao.w));
            a0.x = fmaf(2.f, kv0.x, a0.x); a0.y = fmaf(2.f, kv0.y, a0.y);
            a0.z = fmaf(2.f, kv0.z, a0.z); a0.w = fmaf(2.f, kv0.w, a0.w);
            a1.x = fmaf(2.f, kv1.x, a1.x); a1.y = fmaf(2.f, kv1.y, a1.y);
            a1.z = fmaf(2.f, kv1.z, a1.z); a1.w = fmaf(2.f, kv1.w, a1.w);
            *accp = pack_bf8(a0, a1);
            r40 = kv0; r41 = kv1;
            uint4 ub = P.xw_base[(size_t)n * 4 + c];
            bs0 = bf4_to_f4(make_uint2(ub.x, ub.y));
            bs1 = bf4_to_f4(make_uint2(ub.z, ub.w));
        } else {
            uint4 ao = *accp;
            float4 f0 = bf4_to_f4(make_uint2(ao.x, ao.y));
            float4 f1 = bf4_to_f4(make_uint2(ao.z, ao.w));
            f0.x += kv0.x; f0.y += kv0.y; f0.z += kv0.z; f0.w += kv0.w;
            f1.x += kv1.x; f1.y += kv1.y; f1.z += kv1.z; f1.w += kv1.w;
            int id = P.perm[n];
            size_t o = (size_t)id * DIM + c * 8;
            float4 xc0 = *(const float4*)&P.x_cur[o];
            float4 xc1 = *(const float4*)&P.x_cur[o + 4];
            float4 xn0, xn1;
            xn0.x = fmaf(HS / 6.f, f0.x, xc0.x); xn0.y = fmaf(HS / 6.f, f0.y, xc0.y);
            xn0.z = fmaf(HS / 6.f, f0.z, xc0.z); xn0.w = fmaf(HS / 6.f, f0.w, xc0.w);
            xn1.x = fmaf(HS / 6.f, f1.x, xc1.x); xn1.y = fmaf(HS / 6.f, f1.y, xc1.y);
            xn1.z = fmaf(HS / 6.f, f1.z, xc1.z); xn1.w = fmaf(HS / 6.f, f1.w, xc1.w);
            if (mode == 4) {
                *(float4*)&P.x_cur[o] = xn0;
                *(float4*)&P.x_cur[o + 4] = xn1;
                r40 = f0; r41 = f1;
                uint4 ub = P.xw_base[(size_t)n * 4 + c];
                bs0 = bf4_to_f4(make_uint2(ub.x, ub.y));
                bs1 = bf4_to_f4(make_uint2(ub.z, ub.w));
            } else {
                *(float4*)&P.zout[o] = xn0;
                *(float4*)&P.zout[o + 4] = xn1;
            }
        }
    }

    if (mode == 5) return;

    *(float4*)&sR[nl * 36 + c * 8] = r40;
    *(float4*)&sR[nl * 36 + c * 8 + 4] = r41;
    __syncthreads();
    if (active) {
        float4 y0 = make_float4(0.f, 0.f, 0.f, 0.f);
        float4 y1 = make_float4(0.f, 0.f, 0.f, 0.f);
        const float* row = &sR[nl * 36];
#pragma unroll
        for (int i = 0; i < DIM; i++) {
            float sv = row[i];
            float4 wA = *(const float4*)&sW[i * DIM + c * 8];
            float4 wB = *(const float4*)&sW[i * DIM + c * 8 + 4];
            y0.x = fmaf(sv, wA.x, y0.x); y0.y = fmaf(sv, wA.y, y0.y);
            y0.z = fmaf(sv, wA.z, y0.z); y0.w = fmaf(sv, wA.w, y0.w);
            y1.x = fmaf(sv, wB.x, y1.x); y1.y = fmaf(sv, wB.y, y1.y);
            y1.z = fmaf(sv, wB.z, y1.z); y1.w = fmaf(sv, wB.w, y1.w);
        }
        float sd = A.stage_coef * dn;
        y0.x = fmaf(sd, y0.x, bs0.x); y0.y = fmaf(sd, y0.y, bs0.y);
        y0.z = fmaf(sd, y0.z, bs0.z); y0.w = fmaf(sd, y0.w, bs0.w);
        y1.x = fmaf(sd, y1.x, bs1.x); y1.y = fmaf(sd, y1.y, bs1.y);
        y1.z = fmaf(sd, y1.z, bs1.z); y1.w = fmaf(sd, y1.w, bs1.w);
        P.xw_out[(size_t)n * 4 + c] = pack_bf8(y0, y1);
    }
}

// ---------------- host ----------------

extern "C" void kernel_launch(void* const* d_in, const int* in_sizes, int n_in,
                              void* d_out, int out_size, void* d_ws, size_t ws_size,
                              hipStream_t stream) {
    const float* x   = (const float*)d_in[0];
    const int* epos  = (const int*)d_in[1];
    const int* eneg  = (const int*)d_in[2];
    const float* Wp  = (const float*)d_in[3];
    const float* bp  = (const float*)d_in[4];
    const float* wtp = (const float*)d_in[5];
    const float* Wn  = (const float*)d_in[6];
    const float* bn  = (const float*)d_in[7];
    const float* wtn = (const float*)d_in[8];
    float* out = (float*)d_out;

    char* ws = (char*)d_ws;
    size_t off = 0;
    auto alloc = [&](size_t bytes) -> void* {
        void* p = ws + off;
        off += (bytes + 255) & ~(size_t)255;
        return p;
    };

    struct Sign {
        int *row_ptr, *cnt, *perm, *pos, *gcnt, *btot;
        unsigned* gstage;
        float* dis;
        ushort_t* cw;
        float* x_cur;
        uint4* acc;
        uint4* xwbuf[3];
        const int *src, *dst;
        const float *W, *b, *wt;
        float* zout;
    } S[2];

    const size_t CWCAP = (size_t)NE + 8u * NN;
    int* bint    = (int*)alloc(2 * NBIN * sizeof(int));
    int* binbase = (int*)alloc(2 * NBIN * sizeof(int));

    for (int s = 0; s < 2; s++) {
        S[s].row_ptr  = (int*)alloc((NN + 1) * sizeof(int));
        S[s].cnt      = (int*)alloc(NN * sizeof(int));
        S[s].perm     = (int*)alloc(NN * sizeof(int));
        S[s].pos      = (int*)alloc(NN * sizeof(int));
        S[s].gcnt     = (int*)alloc((size_t)AB * NBIN * sizeof(int));
        S[s].btot     = (int*)alloc(NBIN * sizeof(int));
        S[s].gstage   = (unsigned*)alloc((size_t)NE * sizeof(unsigned));
        S[s].dis      = (float*)alloc(NN * sizeof(float));
        S[s].cw       = (ushort_t*)alloc(CWCAP * sizeof(ushort_t));
        S[s].x_cur    = (float*)alloc((size_t)NN * DIM * sizeof(float));
        S[s].acc      = (uint4*)alloc((size_t)NN * DIM * 2);
        S[s].xwbuf[0] = (uint4*)alloc((size_t)(NN + 1) * DIM * 2);
        S[s].xwbuf[1] = (uint4*)alloc((size_t)(NN + 1) * DIM * 2);
        S[s].xwbuf[2] = (uint4*)alloc((size_t)(NN + 1) * DIM * 2);
    }
    S[0].src = epos; S[0].dst = epos + NE; S[0].W = Wp; S[0].b = bp; S[0].wt = wtp;
    S[0].zout = out;
    S[1].src = eneg; S[1].dst = eneg + NE; S[1].W = Wn; S[1].b = bn; S[1].wt = wtn;
    S[1].zout = out + (size_t)NN * DIM;

    // ---- setup: radix CSR build, bin-local sort (no hist, no global atomics) ----
    k_countA<<<2 * AB, 512, 0, stream>>>(S[0].dst, S[1].dst, S[0].gcnt, S[1].gcnt);
    k_scanM1<<<2 * NBIN, 512, 0, stream>>>(S[0].gcnt, S[1].gcnt, bint);
    k_scanM2<<<1, 256, 0, stream>>>(bint, binbase);
    k_scatA<<<2 * AB, 512, 0, stream>>>(S[0].src, S[0].dst, S[1].src, S[1].dst,
                                        S[0].gcnt, S[1].gcnt, binbase,
                                        S[0].gstage, S[1].gstage);
    k_degB<<<2 * NBIN, 256, 0, stream>>>(S[0].gstage, S[1].gstage, bint, binbase,
                                         S[0].cnt, S[1].cnt, S[0].pos, S[1].pos,
                                         S[0].perm, S[1].perm, S[0].dis, S[1].dis,
                                         S[0].row_ptr, S[1].row_ptr,
                                         S[0].btot, S[1].btot);
    k_binscan<<<2, 256, 0, stream>>>(S[0].btot, S[1].btot);
    k_rowfix<<<2 * NNB, 256, 0, stream>>>(S[0].row_ptr, S[1].row_ptr,
                                          S[0].btot, S[1].btot);
    k_scatB<<<2 * NBIN, 512, 0, stream>>>(S[0].row_ptr, S[1].row_ptr,
                                          S[0].gstage, S[1].gstage,
                                          bint, binbase, S[0].pos, S[1].pos,
                                          S[0].cw, S[1].cw);

    // ---- per-run state init: zero rows, T_base, x_cur = x ----
    ZArgs Z;
    for (int s = 0; s < 2; s++)
        for (int k = 0; k < 3; k++) Z.p[s * 3 + k] = (unsigned*)S[s].xwbuf[k];
    k_zrow<<<1, 96, 0, stream>>>(Z);
    for (int s = 0; s < 2; s++)
        k_matmul<<<cdiv(NN, 32), 256, 0, stream>>>(x, S[s].W, S[s].cnt, S[s].pos,
                                                   (uint2*)S[s].xwbuf[0], S[s].x_cur);

    // ---- RK4 main loop: 4 fused stages per step, both signs per dispatch ----
    for (int st = 0; st < 10; st++) {
        float tb = HS * (float)st;
        struct Ph { float t, sc; int mode, in, out; } ph[4] = {
            { tb,             HS * 0.5f, 1,              0, 1 },
            { tb + HS * 0.5f, HS * 0.5f, 2,              1, 2 },
            { tb + HS * 0.5f, HS,        3,              2, 1 },
            { tb + HS,        HS / 6.f,  st == 9 ? 5 : 4, 1, 0 },
        };
        for (int p = 0; p < 4; p++) {
            StageArgs A;
            for (int s = 0; s < 2; s++) {
                A.s[s].row_ptr = S[s].row_ptr;
                A.s[s].cw      = S[s].cw;
                A.s[s].dis     = S[s].dis;
                A.s[s].perm    = S[s].perm;
                A.s[s].xw_in   = S[s].xwbuf[ph[p].in];
                A.s[s].xw_out  = S[s].xwbuf[ph[p].out];
                A.s[s].xw_base = S[s].xwbuf[0];
                A.s[s].acc     = S[s].acc;
                A.s[s].x_cur   = S[s].x_cur;
                A.s[s].W       = S[s].W;
                A.s[s].b       = S[s].b;
                A.s[s].wt      = S[s].wt;
                A.s[s].zout    = S[s].zout;
            }
            A.t = ph[p].t; A.stage_coef = ph[p].sc; A.mode = ph[p].mode;
            k_stage<<<2 * NBPS, 256, 0, stream>>>(A);
        }
    }
}